// Round 10
// baseline (222.638 us; speedup 1.0000x reference)
//
#include <hip/hip_runtime.h>
#include <hip/hip_fp16.h>
#include <math.h>

namespace {

constexpr int NB = 8192;   // batch B
constexpr int NE = 4096;   // exemplars E
constexpr int ND = 256;    // dim D
constexpr int NT = 128;    // time T
constexpr int NR = 4;      // risks R
constexpr int NK = 64;     // neighbors K
constexpr int NCAND = 320; // candidate cap per row
constexpr float TAUSQ = 4.0f;
constexpr float FEPS = 1e-12f;
constexpr float QS = 256.0f / 4.5f;   // u8 quantization over [0, 4.5)
constexpr float HBIN = 4.5f / 256.f;  // bin width

typedef short s16x8 __attribute__((ext_vector_type(8)));
typedef float f32x4 __attribute__((ext_vector_type(4)));

__device__ __forceinline__ unsigned short f2bf_rne(float f) {
  unsigned int u = __float_as_uint(f);
  unsigned int r = (u + 0x7FFFu + ((u >> 16) & 1u)) >> 16;
  return (unsigned short)r;
}
__device__ __forceinline__ unsigned short f2h(float f) {
  return __half_as_ushort(__float2half(f));
}
__device__ __forceinline__ float h2f(unsigned short s) {
  return __half2float(__ushort_as_half(s));
}

__device__ __forceinline__ void gl_lds16(const void* g, void* lds) {
  __builtin_amdgcn_global_load_lds(
      (const __attribute__((address_space(1))) unsigned int*)g,
      (__attribute__((address_space(3))) unsigned int*)lds, 16, 0, 0);
}

// ---------------- K1: fused prep + split (grid NE+1+ (NB+NE)/2, 128 thr) ----------------
// blocks 0..NE-1: EVh = fp16(exp(log_ev)), ARh = fp16(suffix-sum)
// block NE: baseline bev fp32, bar fp32 (suffix-sum)
// blocks NE+1 ...: bf16 convert + row norms, 2 rows per block
__global__ void k_prep(const float* __restrict__ lev, const float* __restrict__ lcen,
                       const float* __restrict__ lbev, const float* __restrict__ lbcen,
                       unsigned short* __restrict__ EVh, unsigned short* __restrict__ ARh,
                       float* __restrict__ bev, float* __restrict__ bar,
                       const float* __restrict__ x, const float* __restrict__ ex,
                       unsigned short* __restrict__ xh, unsigned short* __restrict__ eh,
                       float* __restrict__ xn, float* __restrict__ exn) {
  __shared__ float wtot;
  int t = threadIdx.x, l = t & 63;
  int bid = blockIdx.x;

  if (bid > NE) {   // ---- split part: 2 rows per block ----
    int r2 = (bid - (NE + 1)) * 2 + (t >> 6);
    bool isx = r2 < NB;
    const float* p = isx ? (x + (size_t)r2 * ND) : (ex + (size_t)(r2 - NB) * ND);
    unsigned short* dst = isx ? (xh + (size_t)r2 * ND) : (eh + (size_t)(r2 - NB) * ND);
    float4 v = reinterpret_cast<const float4*>(p)[l];
    float nv = v.x * v.x + v.y * v.y + v.z * v.z + v.w * v.w;
    ushort4 h4;
    h4.x = f2bf_rne(v.x); h4.y = f2bf_rne(v.y);
    h4.z = f2bf_rne(v.z); h4.w = f2bf_rne(v.w);
    reinterpret_cast<ushort4*>(dst)[l] = h4;
    for (int o = 32; o > 0; o >>= 1) nv += __shfl_down(nv, o);
    if (l == 0) { if (isx) xn[r2] = nv; else exn[r2 - NB] = nv; }
    return;
  }

  int e = bid;
  float acc;
  if (e < NE) {
    acc = expf(lcen[(size_t)e * NT + t]);
    const float* src = lev + ((size_t)e * NT + t) * NR;
    float o0 = expf(src[0]), o1 = expf(src[1]), o2 = expf(src[2]), o3 = expf(src[3]);
    ushort4 h4;
    h4.x = f2h(o0); h4.y = f2h(o1); h4.z = f2h(o2); h4.w = f2h(o3);
    *reinterpret_cast<ushort4*>(EVh + ((size_t)e * NT + t) * NR) = h4;
    acc += o0 + o1 + o2 + o3;
  } else {
    acc = expf(lbcen[t]);
    const float* src = lbev + t * NR;
    float o0 = expf(src[0]), o1 = expf(src[1]), o2 = expf(src[2]), o3 = expf(src[3]);
    bev[t * NR + 0] = o0; bev[t * NR + 1] = o1;
    bev[t * NR + 2] = o2; bev[t * NR + 3] = o3;
    acc += o0 + o1 + o2 + o3;
  }
  // 2-wave suffix-inclusive scan over 128 values
  float v = acc;
  #pragma unroll
  for (int o = 1; o < 64; o <<= 1) {
    float u = __shfl_down(v, o);
    if (l + o < 64) v += u;
  }
  if (t == 64) wtot = v;   // wave1 lane0 = sum of s[64..127]
  __syncthreads();
  if (t < 64) v += wtot;
  if (e < NE) ARh[(size_t)e * NT + t] = f2h(v);
  else        bar[t] = v;
}

// ---------------- K4: bf16 MFMA distance GEMM (K=256, BK=64) -> u8 bins ----------------
// 128x128 tile, 4 waves (2x2), 16x16x32 bf16 MFMA, global_load_lds + XOR swizzle,
// bijective XCD swizzle on the flattened grid.
__global__ __launch_bounds__(256) void k_dist_mfma(
    const unsigned short* __restrict__ xh, const unsigned short* __restrict__ eh,
    const float* __restrict__ xn, const float* __restrict__ exn,
    unsigned char* __restrict__ d2q) {
  __shared__ __align__(16) unsigned char As[128 * 128];  // 128 rows x 64 bf16 (128 B/row)
  __shared__ __align__(16) unsigned char Bs[128 * 128];
  int tid = threadIdx.x;
  int l = tid & 63, w = tid >> 6;
  int wr = w >> 1, wc = w & 1;

  // XCD-aware bijective swizzle: 2048 blocks, 8 XCDs, 256 per chunk
  int lid = blockIdx.x;
  int sl = (lid & 7) * 256 + (lid >> 3);
  int nb = (sl & 31) * 128;    // e-tile (32 tiles)
  int mb = (sl >> 5) * 128;    // b-tile (64 tiles)

  f32x4 acc[4][4];
  #pragma unroll
  for (int m = 0; m < 4; ++m)
    #pragma unroll
    for (int n = 0; n < 4; ++n)
      acc[m][n] = (f32x4){0.f, 0.f, 0.f, 0.f};

  for (int k0 = 0; k0 < ND; k0 += 64) {
    // stage 128 rows x 64 cols per matrix: 1024 chunks of 16B, 4 per thread.
    // linear LDS dest + pre-swizzled global source (slot ^ swz(row), 8 slots/row)
    #pragma unroll
    for (int h = 0; h < 4; ++h) {
      int c = h * 256 + tid;              // wave-uniform base + l*16
      int row = c >> 3, slot = c & 7;
      int swz = (row ^ (row >> 3)) & 7;
      int gcol = k0 + ((slot ^ swz) << 3);
      gl_lds16(xh + (size_t)(mb + row) * ND + gcol, As + c * 16);
      gl_lds16(eh + (size_t)(nb + row) * ND + gcol, Bs + c * 16);
    }
    __syncthreads();
    #pragma unroll
    for (int kk = 0; kk < 2; ++kk) {
      s16x8 af[4], bf_[4];
      int sl0 = kk * 4 + (l >> 4);
      #pragma unroll
      for (int m = 0; m < 4; ++m) {
        int r = wr * 64 + m * 16 + (l & 15);
        int swz = (r ^ (r >> 3)) & 7;
        af[m] = *(const s16x8*)(As + r * 128 + ((sl0 ^ swz) << 4));
      }
      #pragma unroll
      for (int n = 0; n < 4; ++n) {
        int r = wc * 64 + n * 16 + (l & 15);
        int swz = (r ^ (r >> 3)) & 7;
        bf_[n] = *(const s16x8*)(Bs + r * 128 + ((sl0 ^ swz) << 4));
      }
      #pragma unroll
      for (int m = 0; m < 4; ++m)
        #pragma unroll
        for (int n = 0; n < 4; ++n)
          acc[m][n] = __builtin_amdgcn_mfma_f32_16x16x32_bf16(af[m], bf_[n], acc[m][n], 0, 0, 0);
    }
    __syncthreads();
  }

  // epilogue: d2 = xn + exn - 2*dot, quantize u8.  C-map: row=(l>>4)*4+j, col=l&15
  int col0 = nb + wc * 64 + (l & 15);
  int row0 = mb + wr * 64 + (l >> 4) * 4;
  float exnv[4];
  #pragma unroll
  for (int n = 0; n < 4; ++n) exnv[n] = exn[col0 + n * 16];
  #pragma unroll
  for (int m = 0; m < 4; ++m) {
    #pragma unroll
    for (int j = 0; j < 4; ++j) {
      int qrow = row0 + m * 16 + j;
      float xq = xn[qrow];
      #pragma unroll
      for (int n = 0; n < 4; ++n) {
        float d2 = xq + exnv[n] - 2.f * acc[m][n][j];
        int bin = (int)floorf(d2 * QS);
        bin = bin < 0 ? 0 : (bin > 255 ? 255 : bin);
        d2q[(size_t)qrow * NE + (col0 + n * 16)] = (unsigned char)bin;
      }
    }
  }
}

// ---------------- K5: block-per-row exact top-K (membership, no full rank) ----------------
// hist -> threshold bin cb -> compact candidates (bin <= cb+1) -> exact dots ->
// window classify: d < cb*h-h/2 definitely-in; d in window -> small all-pairs; else out.
__global__ __launch_bounds__(256, 8) void k_select(
    const unsigned char* __restrict__ d2q,
    const float* __restrict__ x, const float* __restrict__ ex,
    const float* __restrict__ xn, const float* __restrict__ exn,
    float* __restrict__ selw, int* __restrict__ seli) {
  __shared__ unsigned int hist[256];
  __shared__ float4 xs[64];
  __shared__ int cand_e[NCAND];
  __shared__ float cand_d[NCAND];
  __shared__ unsigned int wsum[4];
  __shared__ int s_cb, s_nc;
  __shared__ int s_m1, s_amb, s_out;
  __shared__ int amb_ci[128];
  __shared__ float amb_dv[128];
  __shared__ unsigned char amb_ok[128];

  int tid = threadIdx.x;
  int l = tid & 63, w = tid >> 6;
  int b = blockIdx.x;

  // coalesced row load: 16 bytes/thread
  uint4 rb = reinterpret_cast<const uint4*>(d2q + (size_t)b * NE)[tid];
  if (tid < 64) xs[tid] = reinterpret_cast<const float4*>(x + (size_t)b * ND)[tid];
  hist[tid] = 0u;
  if (tid == 0) { s_m1 = 0; s_amb = 0; s_out = 0; }
  __syncthreads();

  unsigned int wd[4] = {rb.x, rb.y, rb.z, rb.w};
  #pragma unroll
  for (int c = 0; c < 4; ++c)
    #pragma unroll
    for (int k = 0; k < 4; ++k)
      atomicAdd(&hist[(wd[c] >> (8 * k)) & 255u], 1u);

  // hoist x-row fragments for the dot phase (loop-invariant)
  int g = tid >> 4, gj = tid & 15;
  float4 xr0 = xs[gj], xr1 = xs[gj + 16], xr2 = xs[gj + 32], xr3 = xs[gj + 48];
  __syncthreads();

  // wave 0: prefix over 256 bins (4 per lane) -> smallest bin with cum >= NK
  if (w == 0) {
    unsigned int h0 = hist[l * 4], h1 = hist[l * 4 + 1], h2 = hist[l * 4 + 2], h3 = hist[l * 4 + 3];
    unsigned int gs = h0 + h1 + h2 + h3;
    unsigned int sc = gs;
    #pragma unroll
    for (int o = 1; o < 64; o <<= 1) { unsigned int v = __shfl_up(sc, o); if (l >= o) sc += v; }
    unsigned int excl = sc - gs;
    unsigned int c0 = excl + h0, c1 = c0 + h1, c2 = c1 + h2, c3 = c2 + h3;
    int local = (c0 >= (unsigned)NK) ? 0 : (c1 >= (unsigned)NK) ? 1
              : (c2 >= (unsigned)NK) ? 2 : (c3 >= (unsigned)NK) ? 3 : -1;
    unsigned long long ball = __ballot(local >= 0);
    int first = __ffsll((long long)ball) - 1;   // cum monotone -> first lane = smallest bin
    if (l == first) s_cb = l * 4 + local;
  }
  __syncthreads();
  int cb = s_cb;
  int cbg = cb < 255 ? cb + 1 : 255;   // +1-bin guard band

  // scan-compact candidates (bin <= cbg), ascending element order
  int myc = 0;
  #pragma unroll
  for (int c = 0; c < 4; ++c)
    #pragma unroll
    for (int k = 0; k < 4; ++k)
      myc += ((int)((wd[c] >> (8 * k)) & 255u) <= cbg) ? 1 : 0;
  int sc = myc;
  #pragma unroll
  for (int o = 1; o < 64; o <<= 1) { int v = __shfl_up(sc, o); if (l >= o) sc += v; }
  if (l == 63) wsum[w] = (unsigned)sc;
  __syncthreads();
  int base = 0;
  for (int i = 0; i < w; ++i) base += (int)wsum[i];
  int slot = base + sc - myc;   // exclusive
  #pragma unroll
  for (int c = 0; c < 4; ++c)
    #pragma unroll
    for (int k = 0; k < 4; ++k) {
      int bin = (int)((wd[c] >> (8 * k)) & 255u);
      if (bin <= cbg) {
        if (slot < NCAND) cand_e[slot] = tid * 16 + c * 4 + k;
        ++slot;
      }
    }
  if (tid == 255) s_nc = (base + sc) < NCAND ? (base + sc) : NCAND;
  // zero-init output slots (ordered before emission by the dot-phase barrier)
  if (tid < NK) { selw[(size_t)b * NK + tid] = 0.f; seli[(size_t)b * NK + tid] = 0; }
  __syncthreads();

  int nc = s_nc;
  // exact fp32 dots: one 16-lane group per candidate, 2 candidates per iteration
  float bxn = xn[b];
  for (int c = g; c < nc; c += 32) {
    int eA = cand_e[c];
    int has2 = (c + 16) < nc;
    int eB = has2 ? cand_e[c + 16] : eA;
    const float4* pA = reinterpret_cast<const float4*>(ex + (size_t)eA * ND);
    const float4* pB = reinterpret_cast<const float4*>(ex + (size_t)eB * ND);
    float4 a0 = pA[gj], a1 = pA[gj + 16], a2 = pA[gj + 32], a3 = pA[gj + 48];
    float4 b0 = pB[gj], b1 = pB[gj + 16], b2 = pB[gj + 32], b3 = pB[gj + 48];
    float sA = xr0.x * a0.x + xr0.y * a0.y + xr0.z * a0.z + xr0.w * a0.w
             + xr1.x * a1.x + xr1.y * a1.y + xr1.z * a1.z + xr1.w * a1.w
             + xr2.x * a2.x + xr2.y * a2.y + xr2.z * a2.z + xr2.w * a2.w
             + xr3.x * a3.x + xr3.y * a3.y + xr3.z * a3.z + xr3.w * a3.w;
    float sB = xr0.x * b0.x + xr0.y * b0.y + xr0.z * b0.z + xr0.w * b0.w
             + xr1.x * b1.x + xr1.y * b1.y + xr1.z * b1.z + xr1.w * b1.w
             + xr2.x * b2.x + xr2.y * b2.y + xr2.z * b2.z + xr2.w * b2.w
             + xr3.x * b3.x + xr3.y * b3.y + xr3.z * b3.z + xr3.w * b3.w;
    #pragma unroll
    for (int o = 1; o < 16; o <<= 1) {
      sA += __shfl_xor(sA, o, 16);
      sB += __shfl_xor(sB, o, 16);
    }
    if (gj == 0) {
      cand_d[c] = bxn + exn[eA] - 2.f * sA;
      if (has2) cand_d[c + 16] = bxn + exn[eB] - 2.f * sB;
    }
  }
  __syncthreads();

  // decision window: theta (K-th exact) in (cb*h - E, (cb+1)*h + E], E <= h/2
  float wlo = cb * HBIN - 0.5f * HBIN;
  float whi = (cb + 1) * HBIN + 0.5f * HBIN;

  // classify: definite-in count + collect ambiguous
  for (int i = tid; i < nc; i += 256) {
    float d = cand_d[i];
    if (d < wlo) {
      atomicAdd(&s_m1, 1);
    } else if (d <= whi) {
      int p = atomicAdd(&s_amb, 1);
      if (p < 128) { amb_ci[p] = i; amb_dv[p] = d; }
    }
  }
  __syncthreads();
  int m1 = s_m1;
  int na = s_amb < 128 ? s_amb : 128;
  int need = NK - m1;   // >= 1 by construction

  // small all-pairs among ambiguous (tie-break by candidate index = e index)
  if (tid < na) {
    float di = amb_dv[tid];
    int ci = amb_ci[tid];
    int r = 0;
    for (int j = 0; j < na; ++j) {
      float dj = amb_dv[j];
      r += (dj < di) || (dj == di && amb_ci[j] < ci);
    }
    amb_ok[tid] = (r < need) ? 1 : 0;
  }
  __syncthreads();

  // emit definite-in members (order-free slots; k_out is symmetric over slots)
  for (int i = tid; i < nc; i += 256) {
    float d = cand_d[i];
    if (d < wlo) {
      int p = atomicAdd(&s_out, 1);
      if (p < NK) {
        float sq = fmaxf(d, 0.f);
        selw[(size_t)b * NK + p] = (sq <= TAUSQ) ? expf(-sq) : 0.f;
        seli[(size_t)b * NK + p] = cand_e[i];
      }
    }
  }
  // emit accepted ambiguous
  if (tid < na && amb_ok[tid]) {
    int p = atomicAdd(&s_out, 1);
    if (p < NK) {
      float d = amb_dv[tid];
      float sq = fmaxf(d, 0.f);
      selw[(size_t)b * NK + p] = (sq <= TAUSQ) ? expf(-sq) : 0.f;
      seli[(size_t)b * NK + p] = cand_e[amb_ci[tid]];
    }
  }
}

// ---------------- K6: fp16 gather-accumulate numer/denom, write hazards ----------------
// 2 EV rows per iteration: 128 threads/row, 8 B/lane ushort4 loads (512 B/wave).
__global__ __launch_bounds__(256) void k_out(
    const unsigned short* __restrict__ EVh, const unsigned short* __restrict__ ARh,
    const float* __restrict__ bev, const float* __restrict__ bar,
    const float* __restrict__ selw, const int* __restrict__ seli,
    float* __restrict__ out) {
  __shared__ float wl[NK];
  __shared__ int il[NK];
  __shared__ float snum[NT * NR];
  __shared__ float sden[NT];
  int tid = threadIdx.x;
  int b = blockIdx.x;
  if (tid < NK) { wl[tid] = selw[(size_t)b * NK + tid]; il[tid] = seli[(size_t)b * NK + tid]; }
  __syncthreads();

  int g = tid >> 7;        // group 0: even k, group 1: odd k
  int t = tid & 127;
  float acc0 = 0.f, acc1 = 0.f, acc2 = 0.f, acc3 = 0.f, dacc = 0.f;
  for (int k = g; k < NK; k += 2) {
    float wgt = wl[k];
    int e = il[k];
    ushort4 v = reinterpret_cast<const ushort4*>(EVh + (size_t)e * (NT * NR))[t];
    acc0 += wgt * h2f(v.x);
    acc1 += wgt * h2f(v.y);
    acc2 += wgt * h2f(v.z);
    acc3 += wgt * h2f(v.w);
    dacc += wgt * h2f(ARh[(size_t)e * NT + t]);
  }
  if (g == 0) {
    snum[t * 4 + 0] = acc0; snum[t * 4 + 1] = acc1;
    snum[t * 4 + 2] = acc2; snum[t * 4 + 3] = acc3;
    sden[t] = dacc;
  }
  __syncthreads();
  if (g == 1) {
    snum[t * 4 + 0] += acc0 + bev[t * 4 + 0];
    snum[t * 4 + 1] += acc1 + bev[t * 4 + 1];
    snum[t * 4 + 2] += acc2 + bev[t * 4 + 2];
    snum[t * 4 + 3] += acc3 + bev[t * 4 + 3];
    sden[t] += dacc + bar[t] + FEPS;
  }
  __syncthreads();

  const float lo = FEPS, hi = 1.0f - FEPS;
  {
    int f = tid;
    int tt = f >> 2, r = f & 3;
    float h = snum[f] / sden[tt];
    h = fminf(fmaxf(h, lo), hi);
    out[((size_t)r * NB + b) * NT + tt] = h;       // esh[r][b][t]
    int f1 = tid + 256;
    int t1 = f1 >> 2, r1 = f1 & 3;
    float h1 = snum[f1] / sden[t1];
    h1 = fminf(fmaxf(h1, lo), hi);
    out[((size_t)r1 * NB + b) * NT + t1] = h1;
  }
  if (tid < NT) {
    float sum = snum[4 * tid] + snum[4 * tid + 1] + snum[4 * tid + 2] + snum[4 * tid + 3];
    float ov = sum / sden[tid];
    ov = fminf(fmaxf(ov, lo), hi);
    out[(size_t)4 * NB * NT + (size_t)b * NT + tid] = ov;   // overall[b][t]
  }
}

} // namespace

extern "C" void kernel_launch(void* const* d_in, const int* in_sizes, int n_in,
                              void* d_out, int out_size, void* d_ws, size_t ws_size,
                              hipStream_t stream) {
  (void)in_sizes; (void)n_in; (void)out_size; (void)ws_size;
  const float* x     = (const float*)d_in[0];
  const float* ex    = (const float*)d_in[1];
  const float* lev   = (const float*)d_in[2];
  const float* lcen  = (const float*)d_in[3];
  const float* lbev  = (const float*)d_in[4];
  const float* lbcen = (const float*)d_in[5];
  float* out = (float*)d_out;

  // workspace layout (~48 MiB)
  char* ws = (char*)d_ws;
  unsigned short* EVh = (unsigned short*)(ws);                    // [E][T][R] fp16  4 MiB
  unsigned short* ARh = (unsigned short*)(ws + (4ull << 20));     // [E][T]    fp16  1 MiB
  float* bev = (float*)(ws + (5ull << 20));                       // [T][R]
  float* bar = (float*)(ws + (5ull << 20) + 4096);                // [T]
  float* exn = (float*)(ws + (5ull << 20) + 8192);                // [E]
  float* xn  = (float*)(ws + (5ull << 20) + 8192 + (16u << 10));  // [B]
  unsigned char* d2q = (unsigned char*)(ws + (6ull << 20));       // [B][E] u8  32 MiB
  float* selw = (float*)(ws + (38ull << 20));                     // [B][K]     2 MiB
  int*   seli = (int*)  (ws + (40ull << 20));                     // [B][K]     2 MiB
  unsigned short* xh = (unsigned short*)(ws + (42ull << 20));     // [B][D] bf16 4 MiB
  unsigned short* eh = (unsigned short*)(ws + (46ull << 20));     // [E][D] bf16 2 MiB

  k_prep<<<(NE + 1) + (NB + NE) / 2, NT, 0, stream>>>(
      lev, lcen, lbev, lbcen, EVh, ARh, bev, bar, x, ex, xh, eh, xn, exn);
  k_dist_mfma<<<2048, 256, 0, stream>>>(xh, eh, xn, exn, d2q);
  k_select<<<NB, 256, 0, stream>>>(d2q, x, ex, xn, exn, selw, seli);
  k_out<<<NB, 256, 0, stream>>>(EVh, ARh, bev, bar, selw, seli, out);
}

// Round 11
// 222.325 us; speedup vs baseline: 1.0014x; 1.0014x over previous
//
#include <hip/hip_runtime.h>
#include <hip/hip_fp16.h>
#include <math.h>

namespace {

constexpr int NB = 8192;   // batch B
constexpr int NE = 4096;   // exemplars E
constexpr int ND = 256;    // dim D
constexpr int NT = 128;    // time T
constexpr int NR = 4;      // risks R
constexpr int NK = 64;     // neighbors K
constexpr int NCAND = 320; // candidate cap per row
constexpr float TAUSQ = 4.0f;
constexpr float FEPS = 1e-12f;
constexpr float QS = 256.0f / 4.5f;   // u8 quantization over [0, 4.5)

typedef short s16x8 __attribute__((ext_vector_type(8)));
typedef float f32x4 __attribute__((ext_vector_type(4)));

__device__ __forceinline__ unsigned short f2bf_rne(float f) {
  unsigned int u = __float_as_uint(f);
  unsigned int r = (u + 0x7FFFu + ((u >> 16) & 1u)) >> 16;
  return (unsigned short)r;
}
__device__ __forceinline__ unsigned short f2h(float f) {
  return __half_as_ushort(__float2half(f));
}
__device__ __forceinline__ float h2f(unsigned short s) {
  return __half2float(__ushort_as_half(s));
}

__device__ __forceinline__ void gl_lds16(const void* g, void* lds) {
  __builtin_amdgcn_global_load_lds(
      (const __attribute__((address_space(1))) unsigned int*)g,
      (__attribute__((address_space(3))) unsigned int*)lds, 16, 0, 0);
}

// ---------------- K1: fused prep + split (grid NE+1+ (NB+NE)/2, 128 thr) ----------------
__global__ void k_prep(const float* __restrict__ lev, const float* __restrict__ lcen,
                       const float* __restrict__ lbev, const float* __restrict__ lbcen,
                       unsigned short* __restrict__ EVh, unsigned short* __restrict__ ARh,
                       float* __restrict__ bev, float* __restrict__ bar,
                       const float* __restrict__ x, const float* __restrict__ ex,
                       unsigned short* __restrict__ xh, unsigned short* __restrict__ eh,
                       float* __restrict__ xn, float* __restrict__ exn) {
  __shared__ float wtot;
  int t = threadIdx.x, l = t & 63;
  int bid = blockIdx.x;

  if (bid > NE) {   // ---- split part: 2 rows per block ----
    int r2 = (bid - (NE + 1)) * 2 + (t >> 6);
    bool isx = r2 < NB;
    const float* p = isx ? (x + (size_t)r2 * ND) : (ex + (size_t)(r2 - NB) * ND);
    unsigned short* dst = isx ? (xh + (size_t)r2 * ND) : (eh + (size_t)(r2 - NB) * ND);
    float4 v = reinterpret_cast<const float4*>(p)[l];
    float nv = v.x * v.x + v.y * v.y + v.z * v.z + v.w * v.w;
    ushort4 h4;
    h4.x = f2bf_rne(v.x); h4.y = f2bf_rne(v.y);
    h4.z = f2bf_rne(v.z); h4.w = f2bf_rne(v.w);
    reinterpret_cast<ushort4*>(dst)[l] = h4;
    for (int o = 32; o > 0; o >>= 1) nv += __shfl_down(nv, o);
    if (l == 0) { if (isx) xn[r2] = nv; else exn[r2 - NB] = nv; }
    return;
  }

  int e = bid;
  float acc;
  if (e < NE) {
    acc = expf(lcen[(size_t)e * NT + t]);
    const float* src = lev + ((size_t)e * NT + t) * NR;
    float o0 = expf(src[0]), o1 = expf(src[1]), o2 = expf(src[2]), o3 = expf(src[3]);
    ushort4 h4;
    h4.x = f2h(o0); h4.y = f2h(o1); h4.z = f2h(o2); h4.w = f2h(o3);
    *reinterpret_cast<ushort4*>(EVh + ((size_t)e * NT + t) * NR) = h4;
    acc += o0 + o1 + o2 + o3;
  } else {
    acc = expf(lbcen[t]);
    const float* src = lbev + t * NR;
    float o0 = expf(src[0]), o1 = expf(src[1]), o2 = expf(src[2]), o3 = expf(src[3]);
    bev[t * NR + 0] = o0; bev[t * NR + 1] = o1;
    bev[t * NR + 2] = o2; bev[t * NR + 3] = o3;
    acc += o0 + o1 + o2 + o3;
  }
  // 2-wave suffix-inclusive scan over 128 values
  float v = acc;
  #pragma unroll
  for (int o = 1; o < 64; o <<= 1) {
    float u = __shfl_down(v, o);
    if (l + o < 64) v += u;
  }
  if (t == 64) wtot = v;   // wave1 lane0 = sum of s[64..127]
  __syncthreads();
  if (t < 64) v += wtot;
  if (e < NE) ARh[(size_t)e * NT + t] = f2h(v);
  else        bar[t] = v;
}

// ---------------- K4: bf16 MFMA distance GEMM (K=256, BK=64) -> u8 bins ----------------
__global__ __launch_bounds__(256) void k_dist_mfma(
    const unsigned short* __restrict__ xh, const unsigned short* __restrict__ eh,
    const float* __restrict__ xn, const float* __restrict__ exn,
    unsigned char* __restrict__ d2q) {
  __shared__ __align__(16) unsigned char As[128 * 128];  // 128 rows x 64 bf16 (128 B/row)
  __shared__ __align__(16) unsigned char Bs[128 * 128];
  int tid = threadIdx.x;
  int l = tid & 63, w = tid >> 6;
  int wr = w >> 1, wc = w & 1;

  // XCD-aware bijective swizzle: 2048 blocks, 8 XCDs, 256 per chunk
  int lid = blockIdx.x;
  int sl = (lid & 7) * 256 + (lid >> 3);
  int nb = (sl & 31) * 128;    // e-tile (32 tiles)
  int mb = (sl >> 5) * 128;    // b-tile (64 tiles)

  f32x4 acc[4][4];
  #pragma unroll
  for (int m = 0; m < 4; ++m)
    #pragma unroll
    for (int n = 0; n < 4; ++n)
      acc[m][n] = (f32x4){0.f, 0.f, 0.f, 0.f};

  for (int k0 = 0; k0 < ND; k0 += 64) {
    #pragma unroll
    for (int h = 0; h < 4; ++h) {
      int c = h * 256 + tid;              // wave-uniform base + l*16
      int row = c >> 3, slot = c & 7;
      int swz = (row ^ (row >> 3)) & 7;
      int gcol = k0 + ((slot ^ swz) << 3);
      gl_lds16(xh + (size_t)(mb + row) * ND + gcol, As + c * 16);
      gl_lds16(eh + (size_t)(nb + row) * ND + gcol, Bs + c * 16);
    }
    __syncthreads();
    #pragma unroll
    for (int kk = 0; kk < 2; ++kk) {
      s16x8 af[4], bf_[4];
      int sl0 = kk * 4 + (l >> 4);
      #pragma unroll
      for (int m = 0; m < 4; ++m) {
        int r = wr * 64 + m * 16 + (l & 15);
        int swz = (r ^ (r >> 3)) & 7;
        af[m] = *(const s16x8*)(As + r * 128 + ((sl0 ^ swz) << 4));
      }
      #pragma unroll
      for (int n = 0; n < 4; ++n) {
        int r = wc * 64 + n * 16 + (l & 15);
        int swz = (r ^ (r >> 3)) & 7;
        bf_[n] = *(const s16x8*)(Bs + r * 128 + ((sl0 ^ swz) << 4));
      }
      #pragma unroll
      for (int m = 0; m < 4; ++m)
        #pragma unroll
        for (int n = 0; n < 4; ++n)
          acc[m][n] = __builtin_amdgcn_mfma_f32_16x16x32_bf16(af[m], bf_[n], acc[m][n], 0, 0, 0);
    }
    __syncthreads();
  }

  int col0 = nb + wc * 64 + (l & 15);
  int row0 = mb + wr * 64 + (l >> 4) * 4;
  float exnv[4];
  #pragma unroll
  for (int n = 0; n < 4; ++n) exnv[n] = exn[col0 + n * 16];
  #pragma unroll
  for (int m = 0; m < 4; ++m) {
    #pragma unroll
    for (int j = 0; j < 4; ++j) {
      int qrow = row0 + m * 16 + j;
      float xq = xn[qrow];
      #pragma unroll
      for (int n = 0; n < 4; ++n) {
        float d2 = xq + exnv[n] - 2.f * acc[m][n][j];
        int bin = (int)floorf(d2 * QS);
        bin = bin < 0 ? 0 : (bin > 255 ? 255 : bin);
        d2q[(size_t)qrow * NE + (col0 + n * 16)] = (unsigned char)bin;
      }
    }
  }
}

// ---------------- K5a: hist -> threshold bin (+1 guard) -> scan-compact cand ids ----------------
__global__ __launch_bounds__(256, 8) void k_sel_a(
    const unsigned char* __restrict__ d2q,
    unsigned short* __restrict__ candL, int* __restrict__ candN) {
  __shared__ unsigned int hist[256];
  __shared__ unsigned int wsum[4];
  __shared__ int s_cb;

  int tid = threadIdx.x;
  int l = tid & 63, w = tid >> 6;
  int b = blockIdx.x;

  uint4 rb = reinterpret_cast<const uint4*>(d2q + (size_t)b * NE)[tid];
  hist[tid] = 0u;
  __syncthreads();

  unsigned int wd[4] = {rb.x, rb.y, rb.z, rb.w};
  #pragma unroll
  for (int c = 0; c < 4; ++c)
    #pragma unroll
    for (int k = 0; k < 4; ++k)
      atomicAdd(&hist[(wd[c] >> (8 * k)) & 255u], 1u);
  __syncthreads();

  // wave 0: prefix over 256 bins (4 per lane) -> smallest bin with cum >= NK
  if (w == 0) {
    unsigned int h0 = hist[l * 4], h1 = hist[l * 4 + 1], h2 = hist[l * 4 + 2], h3 = hist[l * 4 + 3];
    unsigned int gs = h0 + h1 + h2 + h3;
    unsigned int sc = gs;
    #pragma unroll
    for (int o = 1; o < 64; o <<= 1) { unsigned int v = __shfl_up(sc, o); if (l >= o) sc += v; }
    unsigned int excl = sc - gs;
    unsigned int c0 = excl + h0, c1 = c0 + h1, c2 = c1 + h2, c3 = c2 + h3;
    int local = (c0 >= (unsigned)NK) ? 0 : (c1 >= (unsigned)NK) ? 1
              : (c2 >= (unsigned)NK) ? 2 : (c3 >= (unsigned)NK) ? 3 : -1;
    unsigned long long ball = __ballot(local >= 0);
    int first = __ffsll((long long)ball) - 1;
    if (l == first) s_cb = l * 4 + local;
  }
  __syncthreads();
  int cbg = s_cb < 255 ? s_cb + 1 : 255;   // +1-bin guard band

  // scan-compact candidate ids (bin <= cbg), ascending element order
  int myc = 0;
  #pragma unroll
  for (int c = 0; c < 4; ++c)
    #pragma unroll
    for (int k = 0; k < 4; ++k)
      myc += ((int)((wd[c] >> (8 * k)) & 255u) <= cbg) ? 1 : 0;
  int sc = myc;
  #pragma unroll
  for (int o = 1; o < 64; o <<= 1) { int v = __shfl_up(sc, o); if (l >= o) sc += v; }
  if (l == 63) wsum[w] = (unsigned)sc;
  __syncthreads();
  int base = 0;
  for (int i = 0; i < w; ++i) base += (int)wsum[i];
  int slot = base + sc - myc;   // exclusive
  unsigned short* cl = candL + (size_t)b * NCAND;
  #pragma unroll
  for (int c = 0; c < 4; ++c)
    #pragma unroll
    for (int k = 0; k < 4; ++k) {
      int bin = (int)((wd[c] >> (8 * k)) & 255u);
      if (bin <= cbg) {
        if (slot < NCAND) cl[slot] = (unsigned short)(tid * 16 + c * 4 + k);
        ++slot;
      }
    }
  if (tid == 255) {
    int nc = base + sc;
    candN[b] = nc < NCAND ? nc : NCAND;
  }
}

// ---------------- K5b: exact dots + full rank + emit (round-5 numerics) ----------------
__global__ __launch_bounds__(256, 8) void k_sel_b(
    const unsigned short* __restrict__ candL, const int* __restrict__ candN,
    const float* __restrict__ x, const float* __restrict__ ex,
    const float* __restrict__ xn, const float* __restrict__ exn,
    float* __restrict__ selw, int* __restrict__ seli) {
  __shared__ int cand_e[NCAND];
  __shared__ float cand_d[NCAND];
  __shared__ int s_nc;

  int tid = threadIdx.x;
  int b = blockIdx.x;
  if (tid == 0) s_nc = candN[b];
  if (tid < NCAND) cand_e[tid] = -1;
  __syncthreads();
  int nc = s_nc;
  if (tid < nc) cand_e[tid] = (int)candL[(size_t)b * NCAND + tid];
  __syncthreads();

  // hoist x fragments per 16-lane group (direct from global; x row is L2-hot)
  int g = tid >> 4, gj = tid & 15;
  const float4* xp = reinterpret_cast<const float4*>(x + (size_t)b * ND);
  float4 xr0 = xp[gj], xr1 = xp[gj + 16], xr2 = xp[gj + 32], xr3 = xp[gj + 48];

  float bxn = xn[b];
  for (int c = g; c < nc; c += 32) {
    int eA = cand_e[c];
    int has2 = (c + 16) < nc;
    int eB = has2 ? cand_e[c + 16] : eA;
    const float4* pA = reinterpret_cast<const float4*>(ex + (size_t)eA * ND);
    const float4* pB = reinterpret_cast<const float4*>(ex + (size_t)eB * ND);
    float4 a0 = pA[gj], a1 = pA[gj + 16], a2 = pA[gj + 32], a3 = pA[gj + 48];
    float4 b0 = pB[gj], b1 = pB[gj + 16], b2 = pB[gj + 32], b3 = pB[gj + 48];
    float sA = xr0.x * a0.x + xr0.y * a0.y + xr0.z * a0.z + xr0.w * a0.w
             + xr1.x * a1.x + xr1.y * a1.y + xr1.z * a1.z + xr1.w * a1.w
             + xr2.x * a2.x + xr2.y * a2.y + xr2.z * a2.z + xr2.w * a2.w
             + xr3.x * a3.x + xr3.y * a3.y + xr3.z * a3.z + xr3.w * a3.w;
    float sB = xr0.x * b0.x + xr0.y * b0.y + xr0.z * b0.z + xr0.w * b0.w
             + xr1.x * b1.x + xr1.y * b1.y + xr1.z * b1.z + xr1.w * b1.w
             + xr2.x * b2.x + xr2.y * b2.y + xr2.z * b2.z + xr2.w * b2.w
             + xr3.x * b3.x + xr3.y * b3.y + xr3.z * b3.z + xr3.w * b3.w;
    #pragma unroll
    for (int o = 1; o < 16; o <<= 1) {
      sA += __shfl_xor(sA, o, 16);
      sB += __shfl_xor(sB, o, 16);
    }
    if (gj == 0) {
      cand_d[c] = bxn + exn[eA] - 2.f * sA;
      if (has2) cand_d[c + 16] = bxn + exn[eB] - 2.f * sB;
    }
  }
  __syncthreads();

  // full rank among candidates (ascending cand_e => index tie-break == top_k)
  for (int i = tid; i < nc; i += 256) {
    float di = cand_d[i];
    int rank = 0;
    for (int j = 0; j < nc; ++j) {
      float dj = cand_d[j];
      rank += (dj < di) || (dj == di && j < i);
    }
    if (rank < NK) {
      float sq = fmaxf(di, 0.f);
      float wgt = (sq <= TAUSQ) ? expf(-sq) : 0.f;
      selw[(size_t)b * NK + rank] = wgt;
      seli[(size_t)b * NK + rank] = cand_e[i];
    }
  }
  if (tid >= nc && tid < NK) {   // degenerate-safety fill
    selw[(size_t)b * NK + tid] = 0.f;
    seli[(size_t)b * NK + tid] = 0;
  }
}

// ---------------- K6: fp16 gather-accumulate numer/denom, write hazards ----------------
__global__ __launch_bounds__(256) void k_out(
    const unsigned short* __restrict__ EVh, const unsigned short* __restrict__ ARh,
    const float* __restrict__ bev, const float* __restrict__ bar,
    const float* __restrict__ selw, const int* __restrict__ seli,
    float* __restrict__ out) {
  __shared__ float wl[NK];
  __shared__ int il[NK];
  __shared__ float snum[NT * NR];
  __shared__ float sden[NT];
  int tid = threadIdx.x;
  int b = blockIdx.x;
  if (tid < NK) { wl[tid] = selw[(size_t)b * NK + tid]; il[tid] = seli[(size_t)b * NK + tid]; }
  __syncthreads();

  int g = tid >> 7;        // group 0: even k, group 1: odd k
  int t = tid & 127;
  float acc0 = 0.f, acc1 = 0.f, acc2 = 0.f, acc3 = 0.f, dacc = 0.f;
  for (int k = g; k < NK; k += 2) {
    float wgt = wl[k];
    int e = il[k];
    ushort4 v = reinterpret_cast<const ushort4*>(EVh + (size_t)e * (NT * NR))[t];
    acc0 += wgt * h2f(v.x);
    acc1 += wgt * h2f(v.y);
    acc2 += wgt * h2f(v.z);
    acc3 += wgt * h2f(v.w);
    dacc += wgt * h2f(ARh[(size_t)e * NT + t]);
  }
  if (g == 0) {
    snum[t * 4 + 0] = acc0; snum[t * 4 + 1] = acc1;
    snum[t * 4 + 2] = acc2; snum[t * 4 + 3] = acc3;
    sden[t] = dacc;
  }
  __syncthreads();
  if (g == 1) {
    snum[t * 4 + 0] += acc0 + bev[t * 4 + 0];
    snum[t * 4 + 1] += acc1 + bev[t * 4 + 1];
    snum[t * 4 + 2] += acc2 + bev[t * 4 + 2];
    snum[t * 4 + 3] += acc3 + bev[t * 4 + 3];
    sden[t] += dacc + bar[t] + FEPS;
  }
  __syncthreads();

  const float lo = FEPS, hi = 1.0f - FEPS;
  {
    int f = tid;
    int tt = f >> 2, r = f & 3;
    float h = snum[f] / sden[tt];
    h = fminf(fmaxf(h, lo), hi);
    out[((size_t)r * NB + b) * NT + tt] = h;       // esh[r][b][t]
    int f1 = tid + 256;
    int t1 = f1 >> 2, r1 = f1 & 3;
    float h1 = snum[f1] / sden[t1];
    h1 = fminf(fmaxf(h1, lo), hi);
    out[((size_t)r1 * NB + b) * NT + t1] = h1;
  }
  if (tid < NT) {
    float sum = snum[4 * tid] + snum[4 * tid + 1] + snum[4 * tid + 2] + snum[4 * tid + 3];
    float ov = sum / sden[tid];
    ov = fminf(fmaxf(ov, lo), hi);
    out[(size_t)4 * NB * NT + (size_t)b * NT + tid] = ov;   // overall[b][t]
  }
}

} // namespace

extern "C" void kernel_launch(void* const* d_in, const int* in_sizes, int n_in,
                              void* d_out, int out_size, void* d_ws, size_t ws_size,
                              hipStream_t stream) {
  (void)in_sizes; (void)n_in; (void)out_size; (void)ws_size;
  const float* x     = (const float*)d_in[0];
  const float* ex    = (const float*)d_in[1];
  const float* lev   = (const float*)d_in[2];
  const float* lcen  = (const float*)d_in[3];
  const float* lbev  = (const float*)d_in[4];
  const float* lbcen = (const float*)d_in[5];
  float* out = (float*)d_out;

  // workspace layout (~54 MiB)
  char* ws = (char*)d_ws;
  unsigned short* EVh = (unsigned short*)(ws);                    // [E][T][R] fp16  4 MiB
  unsigned short* ARh = (unsigned short*)(ws + (4ull << 20));     // [E][T]    fp16  1 MiB
  float* bev = (float*)(ws + (5ull << 20));                       // [T][R]
  float* bar = (float*)(ws + (5ull << 20) + 4096);                // [T]
  float* exn = (float*)(ws + (5ull << 20) + 8192);                // [E]
  float* xn  = (float*)(ws + (5ull << 20) + 8192 + (16u << 10));  // [B]
  unsigned char* d2q = (unsigned char*)(ws + (6ull << 20));       // [B][E] u8  32 MiB
  float* selw = (float*)(ws + (38ull << 20));                     // [B][K]     2 MiB
  int*   seli = (int*)  (ws + (40ull << 20));                     // [B][K]     2 MiB
  unsigned short* xh = (unsigned short*)(ws + (42ull << 20));     // [B][D] bf16 4 MiB
  unsigned short* eh = (unsigned short*)(ws + (46ull << 20));     // [E][D] bf16 2 MiB
  int* candN = (int*)(ws + (48ull << 20));                        // [B]        32 KiB
  unsigned short* candL = (unsigned short*)(ws + (48ull << 20) + (64u << 10)); // [B][NCAND] u16 5 MiB

  k_prep<<<(NE + 1) + (NB + NE) / 2, NT, 0, stream>>>(
      lev, lcen, lbev, lbcen, EVh, ARh, bev, bar, x, ex, xh, eh, xn, exn);
  k_dist_mfma<<<2048, 256, 0, stream>>>(xh, eh, xn, exn, d2q);
  k_sel_a<<<NB, 256, 0, stream>>>(d2q, candL, candN);
  k_sel_b<<<NB, 256, 0, stream>>>(candL, candN, x, ex, xn, exn, selw, seli);
  k_out<<<NB, 256, 0, stream>>>(EVh, ARh, bev, bar, selw, seli, out);
}